// Round 1
// baseline (225.046 us; speedup 1.0000x reference)
//
#include <hip/hip_runtime.h>
#include <hip/hip_bf16.h>

#define Bx 512
#define Lx 256
#define Dx 100
#define Kx 14
#define NNEG 20
#define LNEG 64
// rows of neg ids per batch = NNEG*LNEG = 1280, split into 5 chunks of 256
#define NEG_ROWS 1280
#define NEG_CHUNK 256
#define NEG_SPLITS 5
#define EPAD 257  // LDS stride for eT (odd -> conflict-free)

// ---------------- init: zero the two scalar accumulators ----------------
__global__ void init_kernel(float* acc) {
    if (threadIdx.x < 2) acc[threadIdx.x] = 0.0f;
}

// ---------------- kernel 1: per-batch attention / pt / rs / pos term ----
__global__ __launch_bounds__(256) void attn_kernel(
    const int* __restrict__ pos_ids, const float* __restrict__ table,
    const float* __restrict__ W_att, const float* __restrict__ Wk,
    const float* __restrict__ bk, const float* __restrict__ Wf,
    const float* __restrict__ bf, float* __restrict__ pt_out,
    float* __restrict__ rs_out, float* __restrict__ acc)
{
    const int b = blockIdx.x;
    const int tid = threadIdx.x;

    __shared__ float eT[Dx * EPAD];   // eT[d*EPAD + l], 102,800 B
    __shared__ float fbuf[Lx];
    __shared__ float red[Lx];
    __shared__ float ys_sh[Dx];
    __shared__ float t_sh[Dx];
    __shared__ float zs_sh[Dx];
    __shared__ float pt_sh[Kx];

    // ---- gather e rows into LDS (transposed). 8 groups of 32 lanes,
    // each group loads a row as 25 float4 (400 B contiguous). ----
    {
        const int g = tid >> 5, lane = tid & 31;
        for (int l = g; l < Lx; l += 8) {
            const int id = pos_ids[b * Lx + l];
            if (lane < 25) {
                const float4 v = *reinterpret_cast<const float4*>(
                    table + (size_t)id * Dx + lane * 4);
                const int dbase = lane * 4;
                eT[(dbase + 0) * EPAD + l] = v.x;
                eT[(dbase + 1) * EPAD + l] = v.y;
                eT[(dbase + 2) * EPAD + l] = v.z;
                eT[(dbase + 3) * EPAD + l] = v.w;
            }
        }
    }
    __syncthreads();

    // ---- ys[d] = (1/L) * sum_l e[l][d]  (unmasked mean; padding rows are 0) ----
    if (tid < Dx) {
        const float* row = &eT[tid * EPAD];
        float s0 = 0.f, s1 = 0.f, s2 = 0.f, s3 = 0.f;
        for (int l = 0; l < Lx; l += 4) {
            s0 += row[l + 0]; s1 += row[l + 1];
            s2 += row[l + 2]; s3 += row[l + 3];
        }
        ys_sh[tid] = (s0 + s1 + s2 + s3) * (1.0f / Lx);
    }
    __syncthreads();

    // ---- t[d] = sum_e W_att[d][e] * ys[e] ----
    if (tid < Dx) {
        const float* wrow = W_att + tid * Dx;
        float s = 0.f;
        #pragma unroll 4
        for (int e = 0; e < Dx; ++e) s += wrow[e] * ys_sh[e];
        t_sh[tid] = s;
    }
    __syncthreads();

    // ---- f[l] = mask ? e[l]·t : -1e9 ----
    float fl;
    {
        const int id = pos_ids[b * Lx + tid];
        if (id != 0) {
            float s0 = 0.f, s1 = 0.f;
            for (int d = 0; d < Dx; d += 2) {
                s0 += eT[(d + 0) * EPAD + tid] * t_sh[d + 0];
                s1 += eT[(d + 1) * EPAD + tid] * t_sh[d + 1];
            }
            fl = s0 + s1;
        } else {
            fl = -1e9f;
        }
    }

    // ---- softmax over L (block of 256 = L) ----
    red[tid] = fl;
    __syncthreads();
    for (int s = 128; s > 0; s >>= 1) {
        if (tid < s) red[tid] = fmaxf(red[tid], red[tid + s]);
        __syncthreads();
    }
    const float m = red[0];
    __syncthreads();
    const float p = expf(fl - m);
    red[tid] = p;
    __syncthreads();
    for (int s = 128; s > 0; s >>= 1) {
        if (tid < s) red[tid] += red[tid + s];
        __syncthreads();
    }
    const float S = red[0];
    __syncthreads();
    fbuf[tid] = p / S;   // att[l]
    __syncthreads();

    // ---- zs[d] = sum_l att[l] * e[l][d] ----
    if (tid < Dx) {
        const float* row = &eT[tid * EPAD];
        float s0 = 0.f, s1 = 0.f, s2 = 0.f, s3 = 0.f;
        for (int l = 0; l < Lx; l += 4) {
            s0 += row[l + 0] * fbuf[l + 0];
            s1 += row[l + 1] * fbuf[l + 1];
            s2 += row[l + 2] * fbuf[l + 2];
            s3 += row[l + 3] * fbuf[l + 3];
        }
        zs_sh[tid] = s0 + s1 + s2 + s3;
    }
    __syncthreads();

    // ---- pt[k] = sigmoid(zs·Wk[:,k] + bk[k]) ----
    if (tid < Kx) {
        float s = bk[tid];
        for (int d = 0; d < Dx; ++d) s += zs_sh[d] * Wk[d * Kx + tid];
        const float pk = 1.0f / (1.0f + expf(-s));
        pt_sh[tid] = pk;
        pt_out[b * Kx + tid] = pk;
    }
    __syncthreads();

    // ---- rs[d] = bf[d] + sum_k pt[k]*Wf[k][d]; pos partial = rs·zs ----
    float contrib = 0.f;
    if (tid < Dx) {
        float r = bf[tid];
        #pragma unroll
        for (int k = 0; k < Kx; ++k) r += pt_sh[k] * Wf[k * Dx + tid];
        rs_out[b * Dx + tid] = r;
        contrib = r * zs_sh[tid];
    }
    red[tid] = contrib;
    __syncthreads();
    for (int s = 128; s > 0; s >>= 1) {
        if (tid < s) red[tid] += red[tid + s];
        __syncthreads();
    }
    if (tid == 0) atomicAdd(&acc[0], red[0]);
}

// ---------------- kernel 2: negative-sample term ----------------
__global__ __launch_bounds__(256) void neg_kernel(
    const int* __restrict__ neg_ids, const float* __restrict__ table,
    const float* __restrict__ rs, float* __restrict__ acc)
{
    const int b = blockIdx.x;
    const int c = blockIdx.y;           // chunk of 256 of the 1280 rows
    const int tid = threadIdx.x;

    __shared__ int ids[NEG_CHUNK];
    __shared__ float sbuf[Dx];
    __shared__ float red[256];

    ids[tid] = neg_ids[b * NEG_ROWS + c * NEG_CHUNK + tid];
    __syncthreads();

    const int grp = tid >> 7;           // 0 or 1 (128-thread groups)
    const int idx = tid & 127;          // lanes 0..99 active per group

    float a0 = 0.f, a1 = 0.f;
    if (idx < Dx) {
        // group grp handles rows r ≡ grp (mod 2); 2 accumulators for ILP
        for (int r = grp; r < NEG_CHUNK; r += 4) {
            a0 += table[(size_t)ids[r] * Dx + idx];
            a1 += table[(size_t)ids[r + 2] * Dx + idx];
        }
    }
    const float s = a0 + a1;
    if (grp == 0 && idx < Dx) sbuf[idx] = s;
    __syncthreads();
    if (grp == 1 && idx < Dx) sbuf[idx] += s;
    __syncthreads();

    float v = 0.f;
    if (tid < Dx) v = sbuf[tid] * rs[b * Dx + tid];
    red[tid] = v;
    __syncthreads();
    for (int st = 128; st > 0; st >>= 1) {
        if (tid < st) red[tid] += red[tid + st];
        __syncthreads();
    }
    if (tid == 0) atomicAdd(&acc[1], red[0] * (1.0f / LNEG));
}

// ---------------- kernel 3: reg term + final loss ----------------
__global__ __launch_bounds__(256) void final_kernel(
    const float* __restrict__ Wf, const float* __restrict__ acc,
    float* __restrict__ out)
{
    __shared__ float n[Kx];
    __shared__ float red[256];
    const int tid = threadIdx.x;

    if (tid < Kx) {
        float s = 0.f;
        for (int d = 0; d < Dx; ++d) {
            const float w = Wf[tid * Dx + d];
            s += w * w;
        }
        n[tid] = sqrtf(s);
    }
    __syncthreads();

    float v = 0.f;
    if (tid < Kx * Kx) {
        const int i = tid / Kx;
        const int j = tid - i * Kx;
        const float x = n[i] * n[j] - 1.0f;
        v = x * x;
    }
    red[tid] = v;
    __syncthreads();
    for (int s = 128; s > 0; s >>= 1) {
        if (tid < s) red[tid] += red[tid + s];
        __syncthreads();
    }
    if (tid == 0) {
        const float reg = sqrtf(red[0]);
        const float margin = 1.0f - acc[1] + acc[0];
        out[0] = fmaxf(margin, 0.0f) + reg;   // LAMBDA = 1.0
    }
}

extern "C" void kernel_launch(void* const* d_in, const int* in_sizes, int n_in,
                              void* d_out, int out_size, void* d_ws, size_t ws_size,
                              hipStream_t stream) {
    const int*   pos_ids = (const int*)  d_in[0];
    const int*   neg_ids = (const int*)  d_in[1];
    const float* table   = (const float*)d_in[2];
    const float* W_att   = (const float*)d_in[3];
    const float* Wk      = (const float*)d_in[4];
    const float* bk      = (const float*)d_in[5];
    const float* Wf      = (const float*)d_in[6];
    const float* bf      = (const float*)d_in[7];

    float* out    = (float*)d_out;
    float* pt_out = out + 1;
    float* rs_out = out + 1 + (size_t)Bx * Kx;
    float* acc    = (float*)d_ws;   // acc[0]=pos_term, acc[1]=neg_term

    init_kernel<<<1, 64, 0, stream>>>(acc);
    attn_kernel<<<Bx, 256, 0, stream>>>(pos_ids, table, W_att, Wk, bk, Wf, bf,
                                        pt_out, rs_out, acc);
    dim3 g2(Bx, NEG_SPLITS);
    neg_kernel<<<g2, 256, 0, stream>>>(neg_ids, table, rs_out, acc);
    final_kernel<<<1, 256, 0, stream>>>(Wf, acc, out);
}

// Round 2
// 166.770 us; speedup vs baseline: 1.3494x; 1.3494x over previous
//
#include <hip/hip_runtime.h>
#include <hip/hip_bf16.h>

#define Bx 512
#define Lx 256
#define Dx 100
#define Kx 14
#define NEG_ROWS 1280      // 20 * 64
#define NEG_CHUNKS 10
#define NEG_CHUNK 128      // rows per neg block
#define INTERLEAVE 11      // 1 attn block per 10 neg blocks

// ws layout: acc[0]=pos_term, acc[1]=neg_term, then g[Bx*Dx]
#define G_OFFSET 4
#define ZERO_N (G_OFFSET + Bx * Dx)

// ---------------- init: zero acc + g ----------------
__global__ void init_kernel(float* ws) {
    const int i = blockIdx.x * 256 + threadIdx.x;
    if (i < ZERO_N) ws[i] = 0.0f;
}

// ---------------- fused: attn blocks + neg-gather blocks ----------------
__global__ __launch_bounds__(256) void fused_kernel(
    const int* __restrict__ pos_ids, const int* __restrict__ neg_ids,
    const float* __restrict__ table, const float* __restrict__ W_att,
    const float* __restrict__ Wk, const float* __restrict__ bk,
    const float* __restrict__ Wf, const float* __restrict__ bf,
    float* __restrict__ pt_out, float* __restrict__ rs_out,
    float* __restrict__ ws)
{
    const int tid  = threadIdx.x;
    const int grp  = tid >> 5;      // 0..7
    const int lane = tid & 31;      // 0..31
    const int bid  = blockIdx.x;

    float* acc = ws;
    float* g   = ws + G_OFFSET;

    __shared__ __align__(16) float4 part4[8][26];   // per-group partial vecs
    __shared__ int   ids[Lx];
    __shared__ float fbuf[Lx];
    __shared__ float red[Lx];
    __shared__ __align__(16) float ys_sh[104];
    __shared__ __align__(16) float t_sh[104];
    __shared__ float zs_sh[104];
    __shared__ float pt_sh[Kx];

    float* pf = (float*)part4;      // [8][104] float view

    if (bid % INTERLEAVE != 0) {
        // ================= NEG-GATHER BLOCK =================
        const int j = bid - bid / INTERLEAVE - 1;   // 0..5119
        const int b = j / NEG_CHUNKS;
        const int c = j - b * NEG_CHUNKS;
        const int* idp = neg_ids + (size_t)b * NEG_ROWS + c * NEG_CHUNK;

        if (tid < NEG_CHUNK) ids[tid] = idp[tid];
        __syncthreads();

        float4 a0 = {0.f, 0.f, 0.f, 0.f}, a1 = {0.f, 0.f, 0.f, 0.f};
        if (lane < 25) {
            #pragma unroll 2
            for (int r = grp; r < NEG_CHUNK; r += 16) {
                const float4 v0 = *(const float4*)(table + (size_t)ids[r]     * Dx + lane * 4);
                const float4 v1 = *(const float4*)(table + (size_t)ids[r + 8] * Dx + lane * 4);
                a0.x += v0.x; a0.y += v0.y; a0.z += v0.z; a0.w += v0.w;
                a1.x += v1.x; a1.y += v1.y; a1.z += v1.z; a1.w += v1.w;
            }
            a0.x += a1.x; a0.y += a1.y; a0.z += a1.z; a0.w += a1.w;
            part4[grp][lane] = a0;
        }
        __syncthreads();
        if (tid < Dx) {
            float s = 0.f;
            #pragma unroll
            for (int gg = 0; gg < 8; ++gg) s += pf[gg * 104 + tid];
            atomicAdd(&g[(size_t)b * Dx + tid], s);
        }
        return;
    }

    // ================= ATTN BLOCK =================
    const int b = bid / INTERLEAVE;
    ids[tid] = pos_ids[(size_t)b * Lx + tid];
    __syncthreads();

    // ---- phase A: ys = mean_l e  (gather pass 1) ----
    {
        float4 a0 = {0.f, 0.f, 0.f, 0.f}, a1 = {0.f, 0.f, 0.f, 0.f};
        if (lane < 25) {
            #pragma unroll 2
            for (int r = grp; r < Lx; r += 16) {
                const float4 v0 = *(const float4*)(table + (size_t)ids[r]     * Dx + lane * 4);
                const float4 v1 = *(const float4*)(table + (size_t)ids[r + 8] * Dx + lane * 4);
                a0.x += v0.x; a0.y += v0.y; a0.z += v0.z; a0.w += v0.w;
                a1.x += v1.x; a1.y += v1.y; a1.z += v1.z; a1.w += v1.w;
            }
            a0.x += a1.x; a0.y += a1.y; a0.z += a1.z; a0.w += a1.w;
            part4[grp][lane] = a0;
        }
        __syncthreads();
        if (tid < Dx) {
            float s = 0.f;
            #pragma unroll
            for (int gg = 0; gg < 8; ++gg) s += pf[gg * 104 + tid];
            ys_sh[tid] = s * (1.0f / Lx);
        }
        __syncthreads();
    }

    // ---- t = W_att @ ys ----
    if (tid < Dx) {
        const float* wrow = W_att + (size_t)tid * Dx;
        float s = 0.f;
        #pragma unroll 4
        for (int e = 0; e < Dx; ++e) s += wrow[e] * ys_sh[e];
        t_sh[tid] = s;
    }
    if (tid >= Dx && tid < 104) t_sh[tid] = 0.f;
    __syncthreads();

    // ---- phase B: f[l] = mask ? e_l . t : -1e9  (gather pass 2) ----
    {
        const float4 tl = (lane < 25) ? ((const float4*)t_sh)[lane]
                                      : make_float4(0.f, 0.f, 0.f, 0.f);
        for (int r = grp; r < Lx; r += 16) {
            float d0 = 0.f, d1 = 0.f;
            if (lane < 25) {
                const float4 v0 = *(const float4*)(table + (size_t)ids[r]     * Dx + lane * 4);
                const float4 v1 = *(const float4*)(table + (size_t)ids[r + 8] * Dx + lane * 4);
                d0 = v0.x * tl.x + v0.y * tl.y + v0.z * tl.z + v0.w * tl.w;
                d1 = v1.x * tl.x + v1.y * tl.y + v1.z * tl.z + v1.w * tl.w;
            }
            #pragma unroll
            for (int o = 16; o > 0; o >>= 1) {
                d0 += __shfl_down(d0, o, 32);
                d1 += __shfl_down(d1, o, 32);
            }
            if (lane == 0) {
                fbuf[r]     = (ids[r]     != 0) ? d0 : -1e9f;
                fbuf[r + 8] = (ids[r + 8] != 0) ? d1 : -1e9f;
            }
        }
        __syncthreads();
    }

    // ---- softmax over L ----
    {
        const float fl = fbuf[tid];
        red[tid] = fl;
        __syncthreads();
        for (int s = 128; s > 0; s >>= 1) {
            if (tid < s) red[tid] = fmaxf(red[tid], red[tid + s]);
            __syncthreads();
        }
        const float m = red[0];
        __syncthreads();
        const float p = expf(fl - m);
        red[tid] = p;
        __syncthreads();
        for (int s = 128; s > 0; s >>= 1) {
            if (tid < s) red[tid] += red[tid + s];
            __syncthreads();
        }
        const float S = red[0];
        __syncthreads();
        fbuf[tid] = p / S;    // att[l]
        __syncthreads();
    }

    // ---- phase C: zs = sum_l att_l * e_l  (gather pass 3) ----
    {
        float4 a0 = {0.f, 0.f, 0.f, 0.f}, a1 = {0.f, 0.f, 0.f, 0.f};
        if (lane < 25) {
            for (int r = grp; r < Lx; r += 16) {
                const float w0 = fbuf[r];
                const float w1 = fbuf[r + 8];
                const float4 v0 = *(const float4*)(table + (size_t)ids[r]     * Dx + lane * 4);
                const float4 v1 = *(const float4*)(table + (size_t)ids[r + 8] * Dx + lane * 4);
                a0.x += w0 * v0.x; a0.y += w0 * v0.y; a0.z += w0 * v0.z; a0.w += w0 * v0.w;
                a1.x += w1 * v1.x; a1.y += w1 * v1.y; a1.z += w1 * v1.z; a1.w += w1 * v1.w;
            }
            a0.x += a1.x; a0.y += a1.y; a0.z += a1.z; a0.w += a1.w;
            part4[grp][lane] = a0;
        }
        __syncthreads();
        if (tid < Dx) {
            float s = 0.f;
            #pragma unroll
            for (int gg = 0; gg < 8; ++gg) s += pf[gg * 104 + tid];
            zs_sh[tid] = s;
        }
        __syncthreads();
    }

    // ---- pt = sigmoid(zs @ Wk + bk) ----
    if (tid < Kx) {
        float s = bk[tid];
        for (int d = 0; d < Dx; ++d) s += zs_sh[d] * Wk[d * Kx + tid];
        const float pk = 1.0f / (1.0f + expf(-s));
        pt_sh[tid] = pk;
        pt_out[(size_t)b * Kx + tid] = pk;
    }
    __syncthreads();

    // ---- rs = bf + pt @ Wf ; pos partial = rs . zs ----
    float contrib = 0.f;
    if (tid < Dx) {
        float r = bf[tid];
        #pragma unroll
        for (int k = 0; k < Kx; ++k) r += pt_sh[k] * Wf[k * Dx + tid];
        rs_out[(size_t)b * Dx + tid] = r;
        contrib = r * zs_sh[tid];
    }
    red[tid] = contrib;
    __syncthreads();
    for (int s = 128; s > 0; s >>= 1) {
        if (tid < s) red[tid] += red[tid + s];
        __syncthreads();
    }
    if (tid == 0) atomicAdd(&acc[0], red[0]);
}

// ---------------- dot: neg_term = sum_b g[b].rs[b] / 64 ----------------
__global__ __launch_bounds__(128) void dot_kernel(
    const float* __restrict__ g, const float* __restrict__ rs,
    float* __restrict__ acc)
{
    const int b = blockIdx.x;
    const int tid = threadIdx.x;
    __shared__ float red[128];
    float v = 0.f;
    if (tid < Dx) v = g[(size_t)b * Dx + tid] * rs[(size_t)b * Dx + tid];
    red[tid] = v;
    __syncthreads();
    for (int s = 64; s > 0; s >>= 1) {
        if (tid < s) red[tid] += red[tid + s];
        __syncthreads();
    }
    if (tid == 0) atomicAdd(&acc[1], red[0] * (1.0f / 64.0f));
}

// ---------------- loss: reg term + final ----------------
__global__ __launch_bounds__(256) void loss_kernel(
    const float* __restrict__ Wf, const float* __restrict__ acc,
    float* __restrict__ out)
{
    __shared__ float n[Kx];
    __shared__ float red[256];
    const int tid = threadIdx.x;

    if (tid < Kx) {
        float s = 0.f;
        for (int d = 0; d < Dx; ++d) {
            const float w = Wf[tid * Dx + d];
            s += w * w;
        }
        n[tid] = sqrtf(s);
    }
    __syncthreads();

    float v = 0.f;
    if (tid < Kx * Kx) {
        const int i = tid / Kx;
        const int j = tid - i * Kx;
        const float x = n[i] * n[j] - 1.0f;
        v = x * x;
    }
    red[tid] = v;
    __syncthreads();
    for (int s = 128; s > 0; s >>= 1) {
        if (tid < s) red[tid] += red[tid + s];
        __syncthreads();
    }
    if (tid == 0) {
        const float reg = sqrtf(red[0]);
        const float margin = 1.0f - acc[1] + acc[0];
        out[0] = fmaxf(margin, 0.0f) + reg;   // LAMBDA = 1.0
    }
}

extern "C" void kernel_launch(void* const* d_in, const int* in_sizes, int n_in,
                              void* d_out, int out_size, void* d_ws, size_t ws_size,
                              hipStream_t stream) {
    const int*   pos_ids = (const int*)  d_in[0];
    const int*   neg_ids = (const int*)  d_in[1];
    const float* table   = (const float*)d_in[2];
    const float* W_att   = (const float*)d_in[3];
    const float* Wk      = (const float*)d_in[4];
    const float* bk      = (const float*)d_in[5];
    const float* Wf      = (const float*)d_in[6];
    const float* bf      = (const float*)d_in[7];

    float* out    = (float*)d_out;
    float* pt_out = out + 1;
    float* rs_out = out + 1 + (size_t)Bx * Kx;
    float* ws     = (float*)d_ws;   // acc[2] (+pad), then g[Bx*Dx]
    float* acc    = ws;
    float* g      = ws + G_OFFSET;

    init_kernel<<<(ZERO_N + 255) / 256, 256, 0, stream>>>(ws);
    fused_kernel<<<Bx * INTERLEAVE, 256, 0, stream>>>(
        pos_ids, neg_ids, table, W_att, Wk, bk, Wf, bf, pt_out, rs_out, ws);
    dot_kernel<<<Bx, 128, 0, stream>>>(g, rs_out, acc);
    loss_kernel<<<1, 256, 0, stream>>>(Wf, acc, out);
}

// Round 3
// 147.092 us; speedup vs baseline: 1.5300x; 1.1338x over previous
//
#include <hip/hip_runtime.h>
#include <hip/hip_bf16.h>

#define Bx 512
#define Lx 256
#define Dx 100
#define Kx 14
#define NEG_ROWS 1280      // 20 * 64
#define NEG_CHUNKS 10
#define NEG_CHUNK 128      // rows per neg block
#define INTERLEAVE 11      // 1 attn block per 10 neg blocks

// ws layout: acc[0..3], g[Bx*Dx], then bf16 table [50001*100 ushort]
#define G_OFFSET 4
#define ZERO_N (G_OFFSET + Bx * Dx)          // 51204 floats
#define TBL_ELEMS 5000100                    // 50001 * 100
#define TBL_F4 1250025                       // TBL_ELEMS / 4
#define WS_NEED ((size_t)ZERO_N * 4 + (size_t)TBL_ELEMS * 2)

__device__ __forceinline__ float dot4(float4 a, float4 b) {
    return a.x * b.x + a.y * b.y + a.z * b.z + a.w * b.w;
}

__device__ __forceinline__ float4 ld_bf4(const unsigned short* p) {
    const ushort4 u = *reinterpret_cast<const ushort4*>(p);
    float4 f;
    f.x = __uint_as_float((unsigned)u.x << 16);
    f.y = __uint_as_float((unsigned)u.y << 16);
    f.z = __uint_as_float((unsigned)u.z << 16);
    f.w = __uint_as_float((unsigned)u.w << 16);
    return f;
}

__device__ __forceinline__ unsigned short f2bf(float x) {
    const unsigned u = __float_as_uint(x);
    return (unsigned short)((u + 0x7FFFu + ((u >> 16) & 1u)) >> 16);
}

// ---------------- init: zero acc + g ----------------
__global__ void init_kernel(float* ws) {
    const int i = blockIdx.x * 256 + threadIdx.x;
    if (i < ZERO_N) ws[i] = 0.0f;
}

// ---------------- convert table fp32 -> bf16 ----------------
__global__ __launch_bounds__(256) void convert_kernel(
    const float* __restrict__ table, unsigned short* __restrict__ tb)
{
    const int i = blockIdx.x * 256 + threadIdx.x;
    if (i < TBL_F4) {
        const float4 v = reinterpret_cast<const float4*>(table)[i];
        ushort4 o;
        o.x = f2bf(v.x); o.y = f2bf(v.y); o.z = f2bf(v.z); o.w = f2bf(v.w);
        *reinterpret_cast<ushort4*>(tb + 4 * (size_t)i) = o;
    }
}

// ---------------- fused bf16: attn blocks + neg-gather blocks ----------------
__global__ __launch_bounds__(256) void fused_bf16(
    const int* __restrict__ pos_ids, const int* __restrict__ neg_ids,
    const unsigned short* __restrict__ tb, const float* __restrict__ W_att,
    const float* __restrict__ Wk, const float* __restrict__ bk,
    const float* __restrict__ Wf, const float* __restrict__ bf,
    float* __restrict__ pt_out, float* __restrict__ rs_out,
    float* __restrict__ ws)
{
    const int tid  = threadIdx.x;
    const int grp  = tid >> 5;      // 0..7
    const int lane = tid & 31;      // 0..31
    const int bid  = blockIdx.x;

    float* acc = ws;
    float* g   = ws + G_OFFSET;

    __shared__ __align__(16) float4 part4[8][26];
    __shared__ int   ids[Lx];
    __shared__ float red[Lx];
    __shared__ __align__(16) float ys_sh[104];
    __shared__ __align__(16) float t_sh[104];
    __shared__ float zs_sh[104];
    __shared__ float pt_sh[Kx];
    __shared__ float m_sh[8], s_sh[8], sc_sh[8];

    float* pf = (float*)part4;      // [8][104] float view

    if (bid % INTERLEAVE != 0) {
        // ================= NEG-GATHER BLOCK =================
        const int j = bid - bid / INTERLEAVE - 1;   // 0..5119
        const int b = j / NEG_CHUNKS;
        const int c = j - b * NEG_CHUNKS;
        const int* idp = neg_ids + (size_t)b * NEG_ROWS + c * NEG_CHUNK;

        if (tid < NEG_CHUNK) ids[tid] = idp[tid];
        __syncthreads();

        if (lane < 25) {
            const int o = lane * 4;
            float4 a0 = {0,0,0,0}, a1 = {0,0,0,0}, a2 = {0,0,0,0}, a3 = {0,0,0,0};
            for (int r = grp; r < NEG_CHUNK; r += 32) {
                const float4 v0 = ld_bf4(tb + (size_t)ids[r]      * Dx + o);
                const float4 v1 = ld_bf4(tb + (size_t)ids[r + 8]  * Dx + o);
                const float4 v2 = ld_bf4(tb + (size_t)ids[r + 16] * Dx + o);
                const float4 v3 = ld_bf4(tb + (size_t)ids[r + 24] * Dx + o);
                a0.x += v0.x; a0.y += v0.y; a0.z += v0.z; a0.w += v0.w;
                a1.x += v1.x; a1.y += v1.y; a1.z += v1.z; a1.w += v1.w;
                a2.x += v2.x; a2.y += v2.y; a2.z += v2.z; a2.w += v2.w;
                a3.x += v3.x; a3.y += v3.y; a3.z += v3.z; a3.w += v3.w;
            }
            a0.x += a1.x + a2.x + a3.x; a0.y += a1.y + a2.y + a3.y;
            a0.z += a1.z + a2.z + a3.z; a0.w += a1.w + a2.w + a3.w;
            part4[grp][lane] = a0;
        }
        __syncthreads();
        if (tid < Dx) {
            float s = 0.f;
            #pragma unroll
            for (int gg = 0; gg < 8; ++gg) s += pf[gg * 104 + tid];
            atomicAdd(&g[(size_t)b * Dx + tid], s);
        }
        return;
    }

    // ================= ATTN BLOCK =================
    const int b = bid / INTERLEAVE;
    ids[tid] = pos_ids[(size_t)b * Lx + tid];
    __syncthreads();

    // ---- pass A: ys = mean_l e ----
    if (lane < 25) {
        const int o = lane * 4;
        float4 a0 = {0,0,0,0}, a1 = {0,0,0,0}, a2 = {0,0,0,0}, a3 = {0,0,0,0};
        for (int r = grp; r < Lx; r += 32) {
            const float4 v0 = ld_bf4(tb + (size_t)ids[r]      * Dx + o);
            const float4 v1 = ld_bf4(tb + (size_t)ids[r + 8]  * Dx + o);
            const float4 v2 = ld_bf4(tb + (size_t)ids[r + 16] * Dx + o);
            const float4 v3 = ld_bf4(tb + (size_t)ids[r + 24] * Dx + o);
            a0.x += v0.x; a0.y += v0.y; a0.z += v0.z; a0.w += v0.w;
            a1.x += v1.x; a1.y += v1.y; a1.z += v1.z; a1.w += v1.w;
            a2.x += v2.x; a2.y += v2.y; a2.z += v2.z; a2.w += v2.w;
            a3.x += v3.x; a3.y += v3.y; a3.z += v3.z; a3.w += v3.w;
        }
        a0.x += a1.x + a2.x + a3.x; a0.y += a1.y + a2.y + a3.y;
        a0.z += a1.z + a2.z + a3.z; a0.w += a1.w + a2.w + a3.w;
        part4[grp][lane] = a0;
    }
    __syncthreads();
    if (tid < Dx) {
        float s = 0.f;
        #pragma unroll
        for (int gg = 0; gg < 8; ++gg) s += pf[gg * 104 + tid];
        ys_sh[tid] = s * (1.0f / Lx);
    }
    __syncthreads();

    // ---- t = W_att @ ys ----
    if (tid < Dx) {
        const float* wrow = W_att + (size_t)tid * Dx;
        float s = 0.f;
        #pragma unroll 4
        for (int e = 0; e < Dx; ++e) s += wrow[e] * ys_sh[e];
        t_sh[tid] = s;
    }
    if (tid >= Dx && tid < 104) t_sh[tid] = 0.f;
    __syncthreads();

    // ---- pass B: online softmax, f + zs in one gather ----
    {
        const float4 tl = (lane < 25) ? ((const float4*)t_sh)[lane]
                                      : make_float4(0.f, 0.f, 0.f, 0.f);
        float m = -1e30f, ssum = 0.f;
        float4 za = {0.f, 0.f, 0.f, 0.f};
        for (int r = grp; r < Lx; r += 16) {
            const int id0 = ids[r];
            const int id1 = ids[r + 8];
            float4 e0 = {0,0,0,0}, e1 = {0,0,0,0};
            if (lane < 25) {
                e0 = ld_bf4(tb + (size_t)id0 * Dx + lane * 4);
                e1 = ld_bf4(tb + (size_t)id1 * Dx + lane * 4);
            }
            float d0 = dot4(e0, tl);
            float d1 = dot4(e1, tl);
            #pragma unroll
            for (int o = 16; o > 0; o >>= 1) {
                d0 += __shfl_xor(d0, o, 32);
                d1 += __shfl_xor(d1, o, 32);
            }
            const float f0 = (id0 != 0) ? d0 : -1e30f;
            const float f1 = (id1 != 0) ? d1 : -1e30f;
            const float mn = fmaxf(m, fmaxf(f0, f1));
            const float sc = expf(m - mn);
            const float w0 = (id0 != 0) ? expf(d0 - mn) : 0.f;
            const float w1 = (id1 != 0) ? expf(d1 - mn) : 0.f;
            ssum = ssum * sc + w0 + w1;
            za.x = za.x * sc + w0 * e0.x + w1 * e1.x;
            za.y = za.y * sc + w0 * e0.y + w1 * e1.y;
            za.z = za.z * sc + w0 * e0.z + w1 * e1.z;
            za.w = za.w * sc + w0 * e0.w + w1 * e1.w;
            m = mn;
        }
        if (lane == 0) { m_sh[grp] = m; s_sh[grp] = ssum; }
        if (lane < 25) part4[grp][lane] = za;
    }
    __syncthreads();
    if (tid < 8) {
        float M = -1e30f;
        #pragma unroll
        for (int gg = 0; gg < 8; ++gg) M = fmaxf(M, m_sh[gg]);
        sc_sh[tid] = expf(m_sh[tid] - M);
    }
    __syncthreads();
    if (tid < Dx) {
        float S = 0.f, z = 0.f;
        #pragma unroll
        for (int gg = 0; gg < 8; ++gg) {
            S += s_sh[gg] * sc_sh[gg];
            z += pf[gg * 104 + tid] * sc_sh[gg];
        }
        zs_sh[tid] = z / S;
    }
    __syncthreads();

    // ---- pt = sigmoid(zs @ Wk + bk) ----
    if (tid < Kx) {
        float s = bk[tid];
        for (int d = 0; d < Dx; ++d) s += zs_sh[d] * Wk[d * Kx + tid];
        const float pk = 1.0f / (1.0f + expf(-s));
        pt_sh[tid] = pk;
        pt_out[(size_t)b * Kx + tid] = pk;
    }
    __syncthreads();

    // ---- rs = bf + pt @ Wf ; pos partial = rs . zs ----
    float contrib = 0.f;
    if (tid < Dx) {
        float r = bf[tid];
        #pragma unroll
        for (int k = 0; k < Kx; ++k) r += pt_sh[k] * Wf[k * Dx + tid];
        rs_out[(size_t)b * Dx + tid] = r;
        contrib = r * zs_sh[tid];
    }
    red[tid] = contrib;
    __syncthreads();
    for (int s = 128; s > 0; s >>= 1) {
        if (tid < s) red[tid] += red[tid + s];
        __syncthreads();
    }
    if (tid == 0) atomicAdd(&acc[0], red[0]);
}

// ---------------- fallback fused fp32 (round-2, proven) ----------------
__global__ __launch_bounds__(256) void fused_fp32(
    const int* __restrict__ pos_ids, const int* __restrict__ neg_ids,
    const float* __restrict__ table, const float* __restrict__ W_att,
    const float* __restrict__ Wk, const float* __restrict__ bk,
    const float* __restrict__ Wf, const float* __restrict__ bf,
    float* __restrict__ pt_out, float* __restrict__ rs_out,
    float* __restrict__ ws)
{
    const int tid  = threadIdx.x;
    const int grp  = tid >> 5;
    const int lane = tid & 31;
    const int bid  = blockIdx.x;

    float* acc = ws;
    float* g   = ws + G_OFFSET;

    __shared__ __align__(16) float4 part4[8][26];
    __shared__ int   ids[Lx];
    __shared__ float fbuf[Lx];
    __shared__ float red[Lx];
    __shared__ __align__(16) float ys_sh[104];
    __shared__ __align__(16) float t_sh[104];
    __shared__ float zs_sh[104];
    __shared__ float pt_sh[Kx];

    float* pf = (float*)part4;

    if (bid % INTERLEAVE != 0) {
        const int j = bid - bid / INTERLEAVE - 1;
        const int b = j / NEG_CHUNKS;
        const int c = j - b * NEG_CHUNKS;
        const int* idp = neg_ids + (size_t)b * NEG_ROWS + c * NEG_CHUNK;
        if (tid < NEG_CHUNK) ids[tid] = idp[tid];
        __syncthreads();
        float4 a0 = {0,0,0,0}, a1 = {0,0,0,0};
        if (lane < 25) {
            for (int r = grp; r < NEG_CHUNK; r += 16) {
                const float4 v0 = *(const float4*)(table + (size_t)ids[r]     * Dx + lane * 4);
                const float4 v1 = *(const float4*)(table + (size_t)ids[r + 8] * Dx + lane * 4);
                a0.x += v0.x; a0.y += v0.y; a0.z += v0.z; a0.w += v0.w;
                a1.x += v1.x; a1.y += v1.y; a1.z += v1.z; a1.w += v1.w;
            }
            a0.x += a1.x; a0.y += a1.y; a0.z += a1.z; a0.w += a1.w;
            part4[grp][lane] = a0;
        }
        __syncthreads();
        if (tid < Dx) {
            float s = 0.f;
            #pragma unroll
            for (int gg = 0; gg < 8; ++gg) s += pf[gg * 104 + tid];
            atomicAdd(&g[(size_t)b * Dx + tid], s);
        }
        return;
    }

    const int b = bid / INTERLEAVE;
    ids[tid] = pos_ids[(size_t)b * Lx + tid];
    __syncthreads();
    {
        float4 a0 = {0,0,0,0}, a1 = {0,0,0,0};
        if (lane < 25) {
            for (int r = grp; r < Lx; r += 16) {
                const float4 v0 = *(const float4*)(table + (size_t)ids[r]     * Dx + lane * 4);
                const float4 v1 = *(const float4*)(table + (size_t)ids[r + 8] * Dx + lane * 4);
                a0.x += v0.x; a0.y += v0.y; a0.z += v0.z; a0.w += v0.w;
                a1.x += v1.x; a1.y += v1.y; a1.z += v1.z; a1.w += v1.w;
            }
            a0.x += a1.x; a0.y += a1.y; a0.z += a1.z; a0.w += a1.w;
            part4[grp][lane] = a0;
        }
        __syncthreads();
        if (tid < Dx) {
            float s = 0.f;
            #pragma unroll
            for (int gg = 0; gg < 8; ++gg) s += pf[gg * 104 + tid];
            ys_sh[tid] = s * (1.0f / Lx);
        }
        __syncthreads();
    }
    if (tid < Dx) {
        const float* wrow = W_att + (size_t)tid * Dx;
        float s = 0.f;
        #pragma unroll 4
        for (int e = 0; e < Dx; ++e) s += wrow[e] * ys_sh[e];
        t_sh[tid] = s;
    }
    if (tid >= Dx && tid < 104) t_sh[tid] = 0.f;
    __syncthreads();
    {
        const float4 tl = (lane < 25) ? ((const float4*)t_sh)[lane]
                                      : make_float4(0.f, 0.f, 0.f, 0.f);
        for (int r = grp; r < Lx; r += 16) {
            float d0 = 0.f, d1 = 0.f;
            if (lane < 25) {
                const float4 v0 = *(const float4*)(table + (size_t)ids[r]     * Dx + lane * 4);
                const float4 v1 = *(const float4*)(table + (size_t)ids[r + 8] * Dx + lane * 4);
                d0 = dot4(v0, tl);
                d1 = dot4(v1, tl);
            }
            #pragma unroll
            for (int o = 16; o > 0; o >>= 1) {
                d0 += __shfl_down(d0, o, 32);
                d1 += __shfl_down(d1, o, 32);
            }
            if (lane == 0) {
                fbuf[r]     = (ids[r]     != 0) ? d0 : -1e9f;
                fbuf[r + 8] = (ids[r + 8] != 0) ? d1 : -1e9f;
            }
        }
        __syncthreads();
    }
    {
        const float fl = fbuf[tid];
        red[tid] = fl;
        __syncthreads();
        for (int s = 128; s > 0; s >>= 1) {
            if (tid < s) red[tid] = fmaxf(red[tid], red[tid + s]);
            __syncthreads();
        }
        const float m = red[0];
        __syncthreads();
        const float p = expf(fl - m);
        red[tid] = p;
        __syncthreads();
        for (int s = 128; s > 0; s >>= 1) {
            if (tid < s) red[tid] += red[tid + s];
            __syncthreads();
        }
        const float S = red[0];
        __syncthreads();
        fbuf[tid] = p / S;
        __syncthreads();
    }
    {
        float4 a0 = {0,0,0,0}, a1 = {0,0,0,0};
        if (lane < 25) {
            for (int r = grp; r < Lx; r += 16) {
                const float w0 = fbuf[r];
                const float w1 = fbuf[r + 8];
                const float4 v0 = *(const float4*)(table + (size_t)ids[r]     * Dx + lane * 4);
                const float4 v1 = *(const float4*)(table + (size_t)ids[r + 8] * Dx + lane * 4);
                a0.x += w0 * v0.x; a0.y += w0 * v0.y; a0.z += w0 * v0.z; a0.w += w0 * v0.w;
                a1.x += w1 * v1.x; a1.y += w1 * v1.y; a1.z += w1 * v1.z; a1.w += w1 * v1.w;
            }
            a0.x += a1.x; a0.y += a1.y; a0.z += a1.z; a0.w += a1.w;
            part4[grp][lane] = a0;
        }
        __syncthreads();
        if (tid < Dx) {
            float s = 0.f;
            #pragma unroll
            for (int gg = 0; gg < 8; ++gg) s += pf[gg * 104 + tid];
            zs_sh[tid] = s;
        }
        __syncthreads();
    }
    if (tid < Kx) {
        float s = bk[tid];
        for (int d = 0; d < Dx; ++d) s += zs_sh[d] * Wk[d * Kx + tid];
        const float pk = 1.0f / (1.0f + expf(-s));
        pt_sh[tid] = pk;
        pt_out[(size_t)b * Kx + tid] = pk;
    }
    __syncthreads();
    float contrib = 0.f;
    if (tid < Dx) {
        float r = bf[tid];
        #pragma unroll
        for (int k = 0; k < Kx; ++k) r += pt_sh[k] * Wf[k * Dx + tid];
        rs_out[(size_t)b * Dx + tid] = r;
        contrib = r * zs_sh[tid];
    }
    red[tid] = contrib;
    __syncthreads();
    for (int s = 128; s > 0; s >>= 1) {
        if (tid < s) red[tid] += red[tid + s];
        __syncthreads();
    }
    if (tid == 0) atomicAdd(&acc[0], red[0]);
}

// ---------------- dot: neg_term = sum_b g[b].rs[b] / 64 ----------------
__global__ __launch_bounds__(128) void dot_kernel(
    const float* __restrict__ g, const float* __restrict__ rs,
    float* __restrict__ acc)
{
    const int b = blockIdx.x;
    const int tid = threadIdx.x;
    __shared__ float red[128];
    float v = 0.f;
    if (tid < Dx) v = g[(size_t)b * Dx + tid] * rs[(size_t)b * Dx + tid];
    red[tid] = v;
    __syncthreads();
    for (int s = 64; s > 0; s >>= 1) {
        if (tid < s) red[tid] += red[tid + s];
        __syncthreads();
    }
    if (tid == 0) atomicAdd(&acc[1], red[0] * (1.0f / 64.0f));
}

// ---------------- loss: reg term + final ----------------
__global__ __launch_bounds__(256) void loss_kernel(
    const float* __restrict__ Wf, const float* __restrict__ acc,
    float* __restrict__ out)
{
    __shared__ float n[Kx];
    __shared__ float red[256];
    const int tid = threadIdx.x;

    if (tid < Kx) {
        float s = 0.f;
        for (int d = 0; d < Dx; ++d) {
            const float w = Wf[tid * Dx + d];
            s += w * w;
        }
        n[tid] = sqrtf(s);
    }
    __syncthreads();

    float v = 0.f;
    if (tid < Kx * Kx) {
        const int i = tid / Kx;
        const int j = tid - i * Kx;
        const float x = n[i] * n[j] - 1.0f;
        v = x * x;
    }
    red[tid] = v;
    __syncthreads();
    for (int s = 128; s > 0; s >>= 1) {
        if (tid < s) red[tid] += red[tid + s];
        __syncthreads();
    }
    if (tid == 0) {
        const float reg = sqrtf(red[0]);
        const float margin = 1.0f - acc[1] + acc[0];
        out[0] = fmaxf(margin, 0.0f) + reg;   // LAMBDA = 1.0
    }
}

extern "C" void kernel_launch(void* const* d_in, const int* in_sizes, int n_in,
                              void* d_out, int out_size, void* d_ws, size_t ws_size,
                              hipStream_t stream) {
    const int*   pos_ids = (const int*)  d_in[0];
    const int*   neg_ids = (const int*)  d_in[1];
    const float* table   = (const float*)d_in[2];
    const float* W_att   = (const float*)d_in[3];
    const float* Wk      = (const float*)d_in[4];
    const float* bk      = (const float*)d_in[5];
    const float* Wf      = (const float*)d_in[6];
    const float* bf      = (const float*)d_in[7];

    float* out    = (float*)d_out;
    float* pt_out = out + 1;
    float* rs_out = out + 1 + (size_t)Bx * Kx;
    float* ws     = (float*)d_ws;
    float* acc    = ws;
    float* g      = ws + G_OFFSET;
    unsigned short* tb = (unsigned short*)(ws + ZERO_N);

    init_kernel<<<(ZERO_N + 255) / 256, 256, 0, stream>>>(ws);

    if (ws_size >= WS_NEED) {
        convert_kernel<<<(TBL_F4 + 255) / 256, 256, 0, stream>>>(table, tb);
        fused_bf16<<<Bx * INTERLEAVE, 256, 0, stream>>>(
            pos_ids, neg_ids, tb, W_att, Wk, bk, Wf, bf, pt_out, rs_out, ws);
    } else {
        fused_fp32<<<Bx * INTERLEAVE, 256, 0, stream>>>(
            pos_ids, neg_ids, table, W_att, Wk, bk, Wf, bf, pt_out, rs_out, ws);
    }
    dot_kernel<<<Bx, 128, 0, stream>>>(g, rs_out, acc);
    loss_kernel<<<1, 256, 0, stream>>>(Wf, acc, out);
}

// Round 4
// 145.630 us; speedup vs baseline: 1.5453x; 1.0100x over previous
//
#include <hip/hip_runtime.h>
#include <hip/hip_bf16.h>

#define Bx 512
#define Lx 256
#define Dx 100
#define Kx 14
#define VROWS 50001        // vocab + padding row
#define NEG_ROWS 1280      // 20 * 64
#define NEG_CHUNKS 10
#define NEG_CHUNK 128      // rows per neg block
#define NBLK_ATTN Bx
#define NBLK_NEG (Bx * NEG_CHUNKS)
#define ACC_N (4 + Bx * Dx)   // acc[0..3] + g[Bx*Dx] = 51204 floats

#define PAD_STRIDE 128     // ushorts per row, padded: 256 B, 2 lines exact
#define RAW_STRIDE 100     // ushorts per row, compact fallback

// ws layout: [ bf16 table VROWS*RS ushorts ][ acc 4 floats ][ g Bx*Dx floats ]
static inline size_t ws_need(int rs) {
    return (size_t)VROWS * rs * 2 + (size_t)ACC_N * 4;
}

__device__ __forceinline__ float dot4(float4 a, float4 b) {
    return a.x * b.x + a.y * b.y + a.z * b.z + a.w * b.w;
}

__device__ __forceinline__ float4 ld_bf4(const unsigned short* p) {
    const ushort4 u = *reinterpret_cast<const ushort4*>(p);
    float4 f;
    f.x = __uint_as_float((unsigned)u.x << 16);
    f.y = __uint_as_float((unsigned)u.y << 16);
    f.z = __uint_as_float((unsigned)u.z << 16);
    f.w = __uint_as_float((unsigned)u.w << 16);
    return f;
}

__device__ __forceinline__ unsigned short f2bf(float x) {
    const unsigned u = __float_as_uint(x);
    return (unsigned short)((u + 0x7FFFu + ((u >> 16) & 1u)) >> 16);
}

// ---- convert fp32 table -> bf16 rows of stride RS; also zero acc+g ----
__global__ __launch_bounds__(256) void convert_kernel(
    const float* __restrict__ table, unsigned short* __restrict__ tb,
    float* __restrict__ acc, int RS, int nslots)
{
    const int gid = blockIdx.x * 256 + threadIdx.x;
    if (gid < ACC_N) acc[gid] = 0.0f;
    if (gid >= nslots) return;
    const int spr = RS >> 2;                 // ushort4 slots per row
    const int row = gid / spr;
    const int c   = gid - row * spr;
    ushort4 o = {0, 0, 0, 0};
    if (c < 25) {
        const float4 v = *reinterpret_cast<const float4*>(
            table + (size_t)row * Dx + c * 4);
        o.x = f2bf(v.x); o.y = f2bf(v.y); o.z = f2bf(v.z); o.w = f2bf(v.w);
    }
    *reinterpret_cast<ushort4*>(tb + 4 * (size_t)gid) = o;
}

// ---- fused: attn blocks (bid < Bx) + neg-gather blocks ----
__global__ __launch_bounds__(256) void fused_bf16(
    const int* __restrict__ pos_ids, const int* __restrict__ neg_ids,
    const unsigned short* __restrict__ tb, const float* __restrict__ W_att,
    const float* __restrict__ Wk, const float* __restrict__ bk,
    const float* __restrict__ Wf, const float* __restrict__ bf,
    float* __restrict__ pt_out, float* __restrict__ rs_out,
    float* __restrict__ acc, float* __restrict__ g, int RS)
{
    const int tid  = threadIdx.x;
    const int grp  = tid >> 5;      // 0..7
    const int lane = tid & 31;      // 0..31
    const int bid  = blockIdx.x;

    __shared__ __align__(16) float4 part4[8][26];
    __shared__ int   ids[Lx];
    __shared__ float red[Lx];
    __shared__ __align__(16) float ys_sh[104];
    __shared__ __align__(16) float t_sh[104];
    __shared__ float zs_sh[104];
    __shared__ float pt_sh[Kx];
    __shared__ float m_sh[8], s_sh[8], sc_sh[8];

    float* pf = (float*)part4;      // [8][104] float view

    if (bid >= NBLK_ATTN) {
        // ================= NEG-GATHER BLOCK =================
        const int j = bid - NBLK_ATTN;              // 0..5119
        const int b = j / NEG_CHUNKS;
        const int c = j - b * NEG_CHUNKS;
        const int* idp = neg_ids + (size_t)b * NEG_ROWS + c * NEG_CHUNK;

        if (tid < NEG_CHUNK) ids[tid] = idp[tid];
        __syncthreads();

        if (lane < 25) {
            const int o = lane * 4;
            float4 a0 = {0,0,0,0}, a1 = {0,0,0,0}, a2 = {0,0,0,0}, a3 = {0,0,0,0};
            for (int r = grp; r < NEG_CHUNK; r += 32) {
                const float4 v0 = ld_bf4(tb + (size_t)ids[r]      * RS + o);
                const float4 v1 = ld_bf4(tb + (size_t)ids[r + 8]  * RS + o);
                const float4 v2 = ld_bf4(tb + (size_t)ids[r + 16] * RS + o);
                const float4 v3 = ld_bf4(tb + (size_t)ids[r + 24] * RS + o);
                a0.x += v0.x; a0.y += v0.y; a0.z += v0.z; a0.w += v0.w;
                a1.x += v1.x; a1.y += v1.y; a1.z += v1.z; a1.w += v1.w;
                a2.x += v2.x; a2.y += v2.y; a2.z += v2.z; a2.w += v2.w;
                a3.x += v3.x; a3.y += v3.y; a3.z += v3.z; a3.w += v3.w;
            }
            a0.x += a1.x + a2.x + a3.x; a0.y += a1.y + a2.y + a3.y;
            a0.z += a1.z + a2.z + a3.z; a0.w += a1.w + a2.w + a3.w;
            part4[grp][lane] = a0;
        }
        __syncthreads();
        if (tid < Dx) {
            float s = 0.f;
            #pragma unroll
            for (int gg = 0; gg < 8; ++gg) s += pf[gg * 104 + tid];
            atomicAdd(&g[(size_t)b * Dx + tid], s);
        }
        return;
    }

    // ================= ATTN BLOCK =================
    const int b = bid;
    ids[tid] = pos_ids[(size_t)b * Lx + tid];
    __syncthreads();

    // ---- pass A: ys = mean_l e ----
    if (lane < 25) {
        const int o = lane * 4;
        float4 a0 = {0,0,0,0}, a1 = {0,0,0,0}, a2 = {0,0,0,0}, a3 = {0,0,0,0};
        for (int r = grp; r < Lx; r += 32) {
            const float4 v0 = ld_bf4(tb + (size_t)ids[r]      * RS + o);
            const float4 v1 = ld_bf4(tb + (size_t)ids[r + 8]  * RS + o);
            const float4 v2 = ld_bf4(tb + (size_t)ids[r + 16] * RS + o);
            const float4 v3 = ld_bf4(tb + (size_t)ids[r + 24] * RS + o);
            a0.x += v0.x; a0.y += v0.y; a0.z += v0.z; a0.w += v0.w;
            a1.x += v1.x; a1.y += v1.y; a1.z += v1.z; a1.w += v1.w;
            a2.x += v2.x; a2.y += v2.y; a2.z += v2.z; a2.w += v2.w;
            a3.x += v3.x; a3.y += v3.y; a3.z += v3.z; a3.w += v3.w;
        }
        a0.x += a1.x + a2.x + a3.x; a0.y += a1.y + a2.y + a3.y;
        a0.z += a1.z + a2.z + a3.z; a0.w += a1.w + a2.w + a3.w;
        part4[grp][lane] = a0;
    }
    __syncthreads();
    if (tid < Dx) {
        float s = 0.f;
        #pragma unroll
        for (int gg = 0; gg < 8; ++gg) s += pf[gg * 104 + tid];
        ys_sh[tid] = s * (1.0f / Lx);
    }
    __syncthreads();

    // ---- t = W_att @ ys ----
    if (tid < Dx) {
        const float* wrow = W_att + (size_t)tid * Dx;
        float s = 0.f;
        #pragma unroll 4
        for (int e = 0; e < Dx; ++e) s += wrow[e] * ys_sh[e];
        t_sh[tid] = s;
    }
    if (tid >= Dx && tid < 104) t_sh[tid] = 0.f;
    __syncthreads();

    // ---- pass B: online softmax, f + zs in one gather ----
    {
        const float4 tl = (lane < 25) ? ((const float4*)t_sh)[lane]
                                      : make_float4(0.f, 0.f, 0.f, 0.f);
        float m = -1e30f, ssum = 0.f;
        float4 za = {0.f, 0.f, 0.f, 0.f};
        for (int r = grp; r < Lx; r += 16) {
            const int id0 = ids[r];
            const int id1 = ids[r + 8];
            float4 e0 = {0,0,0,0}, e1 = {0,0,0,0};
            if (lane < 25) {
                e0 = ld_bf4(tb + (size_t)id0 * RS + lane * 4);
                e1 = ld_bf4(tb + (size_t)id1 * RS + lane * 4);
            }
            float d0 = dot4(e0, tl);
            float d1 = dot4(e1, tl);
            #pragma unroll
            for (int o = 16; o > 0; o >>= 1) {
                d0 += __shfl_xor(d0, o, 32);
                d1 += __shfl_xor(d1, o, 32);
            }
            const float f0 = (id0 != 0) ? d0 : -1e30f;
            const float f1 = (id1 != 0) ? d1 : -1e30f;
            const float mn = fmaxf(m, fmaxf(f0, f1));
            const float sc = expf(m - mn);
            const float w0 = (id0 != 0) ? expf(d0 - mn) : 0.f;
            const float w1 = (id1 != 0) ? expf(d1 - mn) : 0.f;
            ssum = ssum * sc + w0 + w1;
            za.x = za.x * sc + w0 * e0.x + w1 * e1.x;
            za.y = za.y * sc + w0 * e0.y + w1 * e1.y;
            za.z = za.z * sc + w0 * e0.z + w1 * e1.z;
            za.w = za.w * sc + w0 * e0.w + w1 * e1.w;
            m = mn;
        }
        if (lane == 0) { m_sh[grp] = m; s_sh[grp] = ssum; }
        if (lane < 25) part4[grp][lane] = za;
    }
    __syncthreads();
    if (tid < 8) {
        float M = -1e30f;
        #pragma unroll
        for (int gg = 0; gg < 8; ++gg) M = fmaxf(M, m_sh[gg]);
        sc_sh[tid] = expf(m_sh[tid] - M);
    }
    __syncthreads();
    if (tid < Dx) {
        float S = 0.f, z = 0.f;
        #pragma unroll
        for (int gg = 0; gg < 8; ++gg) {
            S += s_sh[gg] * sc_sh[gg];
            z += pf[gg * 104 + tid] * sc_sh[gg];
        }
        zs_sh[tid] = z / S;
    }
    __syncthreads();

    // ---- pt = sigmoid(zs @ Wk + bk) ----
    if (tid < Kx) {
        float s = bk[tid];
        for (int d = 0; d < Dx; ++d) s += zs_sh[d] * Wk[d * Kx + tid];
        const float pk = 1.0f / (1.0f + expf(-s));
        pt_sh[tid] = pk;
        pt_out[(size_t)b * Kx + tid] = pk;
    }
    __syncthreads();

    // ---- rs = bf + pt @ Wf ; pos partial = rs . zs ----
    float contrib = 0.f;
    if (tid < Dx) {
        float r = bf[tid];
        #pragma unroll
        for (int k = 0; k < Kx; ++k) r += pt_sh[k] * Wf[k * Dx + tid];
        rs_out[(size_t)b * Dx + tid] = r;
        contrib = r * zs_sh[tid];
    }
    red[tid] = contrib;
    __syncthreads();
    for (int s = 128; s > 0; s >>= 1) {
        if (tid < s) red[tid] += red[tid + s];
        __syncthreads();
    }
    if (tid == 0) atomicAdd(&acc[0], red[0]);
}

// ---- loss: neg dot + reg term + final (single block, 1024 threads) ----
__global__ __launch_bounds__(1024) void loss_kernel(
    const float* __restrict__ Wf, const float* __restrict__ acc,
    const float* __restrict__ g, const float* __restrict__ rs,
    float* __restrict__ out)
{
    __shared__ float n[Kx];
    __shared__ float red[1024];
    const int tid = threadIdx.x;

    // neg dot: sum over Bx*Dx of g*rs
    float v = 0.f;
    for (int i = tid; i < Bx * Dx; i += 1024) v += g[i] * rs[i];
    red[tid] = v;
    __syncthreads();
    for (int s = 512; s > 0; s >>= 1) {
        if (tid < s) red[tid] += red[tid + s];
        __syncthreads();
    }
    const float neg_term = red[0] * (1.0f / 64.0f);
    __syncthreads();

    if (tid < Kx) {
        float s = 0.f;
        for (int d = 0; d < Dx; ++d) {
            const float w = Wf[tid * Dx + d];
            s += w * w;
        }
        n[tid] = sqrtf(s);
    }
    __syncthreads();

    float vv = 0.f;
    if (tid < Kx * Kx) {
        const int i = tid / Kx;
        const int j = tid - i * Kx;
        const float x = n[i] * n[j] - 1.0f;
        vv = x * x;
    }
    red[tid] = vv;
    __syncthreads();
    for (int s = 512; s > 0; s >>= 1) {
        if (tid < s) red[tid] += red[tid + s];
        __syncthreads();
    }
    if (tid == 0) {
        const float reg = sqrtf(red[0]);
        const float margin = 1.0f - neg_term + acc[0];
        out[0] = fmaxf(margin, 0.0f) + reg;   // LAMBDA = 1.0
    }
}

extern "C" void kernel_launch(void* const* d_in, const int* in_sizes, int n_in,
                              void* d_out, int out_size, void* d_ws, size_t ws_size,
                              hipStream_t stream) {
    const int*   pos_ids = (const int*)  d_in[0];
    const int*   neg_ids = (const int*)  d_in[1];
    const float* table   = (const float*)d_in[2];
    const float* W_att   = (const float*)d_in[3];
    const float* Wk      = (const float*)d_in[4];
    const float* bk      = (const float*)d_in[5];
    const float* Wf      = (const float*)d_in[6];
    const float* bf      = (const float*)d_in[7];

    float* out    = (float*)d_out;
    float* pt_out = out + 1;
    float* rs_out = out + 1 + (size_t)Bx * Kx;

    // pick row stride: padded 256 B rows if ws allows, else compact
    const int RS = (ws_size >= ws_need(PAD_STRIDE)) ? PAD_STRIDE : RAW_STRIDE;

    unsigned short* tb = (unsigned short*)d_ws;
    float* acc = (float*)d_ws + ((size_t)VROWS * RS) / 2;  // RS even -> exact
    float* g   = acc + 4;

    const int nslots = VROWS * (RS >> 2);
    convert_kernel<<<(nslots + 255) / 256, 256, 0, stream>>>(
        table, tb, acc, RS, nslots);
    fused_bf16<<<NBLK_ATTN + NBLK_NEG, 256, 0, stream>>>(
        pos_ids, neg_ids, tb, W_att, Wk, bk, Wf, bf,
        pt_out, rs_out, acc, g, RS);
    loss_kernel<<<1, 1024, 0, stream>>>(Wf, acc, g, rs_out, out);
}

// Round 5
// 138.389 us; speedup vs baseline: 1.6262x; 1.0523x over previous
//
#include <hip/hip_runtime.h>
#include <hip/hip_bf16.h>

#if !__has_builtin(__builtin_amdgcn_cvt_pk_f32_fp8) || !__has_builtin(__builtin_amdgcn_cvt_pk_fp8_f32)
#include <hip/hip_fp8.h>
#endif

#define Bx 512
#define Lx 256
#define Dx 100
#define Kx 14
#define VROWS 50001        // vocab + padding row
#define NEG_ROWS 1280      // 20 * 64
#define NEG_CHUNKS 5
#define NEG_CHUNK 256      // rows per neg block
#define NBLK_ATTN Bx
#define NBLK_NEG (Bx * NEG_CHUNKS)
#define ACC_N (4 + Bx * Dx)   // acc[0..3] + g[Bx*Dx]

#define PAD16 128          // ushorts per bf16 row (256 B, 2 lines exact)
#define PAD8  128          // bytes per fp8 row (128 B, 1 line exact)
#define RAW16 100
#define RAW8  100

typedef float floatx2 __attribute__((ext_vector_type(2)));

__device__ __forceinline__ float dot4(float4 a, float4 b) {
    return a.x * b.x + a.y * b.y + a.z * b.z + a.w * b.w;
}

__device__ __forceinline__ float4 ld_bf4(const unsigned short* p) {
    const ushort4 u = *reinterpret_cast<const ushort4*>(p);
    float4 f;
    f.x = __uint_as_float((unsigned)u.x << 16);
    f.y = __uint_as_float((unsigned)u.y << 16);
    f.z = __uint_as_float((unsigned)u.z << 16);
    f.w = __uint_as_float((unsigned)u.w << 16);
    return f;
}

__device__ __forceinline__ unsigned short f2bf(float x) {
    const unsigned u = __float_as_uint(x);
    return (unsigned short)((u + 0x7FFFu + ((u >> 16) & 1u)) >> 16);
}

__device__ __forceinline__ float4 fp8x4_dec(unsigned u) {
#if __has_builtin(__builtin_amdgcn_cvt_pk_f32_fp8)
    floatx2 lo = __builtin_amdgcn_cvt_pk_f32_fp8((int)u, false);
    floatx2 hi = __builtin_amdgcn_cvt_pk_f32_fp8((int)u, true);
    return make_float4(lo.x, lo.y, hi.x, hi.y);
#else
    __hip_fp8_e4m3 a, b, c, d;
    a.__x = (unsigned char)(u & 0xFF);
    b.__x = (unsigned char)((u >> 8) & 0xFF);
    c.__x = (unsigned char)((u >> 16) & 0xFF);
    d.__x = (unsigned char)((u >> 24) & 0xFF);
    return make_float4((float)a, (float)b, (float)c, (float)d);
#endif
}

__device__ __forceinline__ unsigned fp8x4_enc(float4 v) {
#if __has_builtin(__builtin_amdgcn_cvt_pk_fp8_f32)
    int p = 0;
    p = __builtin_amdgcn_cvt_pk_fp8_f32(v.x, v.y, p, false);
    p = __builtin_amdgcn_cvt_pk_fp8_f32(v.z, v.w, p, true);
    return (unsigned)p;
#else
    __hip_fp8_e4m3 a(v.x), b(v.y), c(v.z), d(v.w);
    return (unsigned)a.__x | ((unsigned)b.__x << 8) |
           ((unsigned)c.__x << 16) | ((unsigned)d.__x << 24);
#endif
}

// ---- convert fp32 table -> bf16 rows (stride RS16 ushorts) + fp8 rows
// ---- (stride RS8 bytes); also zero acc+g ----
__global__ __launch_bounds__(256) void convert_kernel(
    const float* __restrict__ table, unsigned short* __restrict__ tb16,
    unsigned char* __restrict__ tb8, float* __restrict__ acc,
    int RS16, int RS8, int padded)
{
    const int gid = blockIdx.x * 256 + threadIdx.x;
    if (gid < ACC_N) acc[gid] = 0.0f;
    const int row = gid >> 5;          // 32 slots per row
    const int c   = gid & 31;
    if (row >= VROWS) return;
    if (c < 25) {
        const float4 v = *reinterpret_cast<const float4*>(
            table + (size_t)row * Dx + c * 4);
        ushort4 o;
        o.x = f2bf(v.x); o.y = f2bf(v.y); o.z = f2bf(v.z); o.w = f2bf(v.w);
        *reinterpret_cast<ushort4*>(tb16 + (size_t)row * RS16 + c * 4) = o;
        *reinterpret_cast<unsigned*>(tb8 + (size_t)row * RS8 + c * 4) = fp8x4_enc(v);
    } else if (padded) {
        ushort4 z = {0, 0, 0, 0};
        *reinterpret_cast<ushort4*>(tb16 + (size_t)row * RS16 + c * 4) = z;
        *reinterpret_cast<unsigned*>(tb8 + (size_t)row * RS8 + c * 4) = 0u;
    }
}

// ---- fused: attn blocks (bid < Bx) + neg-gather blocks ----
__global__ __launch_bounds__(256) void fused_gather(
    const int* __restrict__ pos_ids, const int* __restrict__ neg_ids,
    const unsigned short* __restrict__ tb16, const unsigned char* __restrict__ tb8,
    const float* __restrict__ W_att, const float* __restrict__ Wk,
    const float* __restrict__ bk, const float* __restrict__ Wf,
    const float* __restrict__ bf, float* __restrict__ pt_out,
    float* __restrict__ rs_out, float* __restrict__ acc, float* __restrict__ g,
    int RS16, int RS8)
{
    const int tid  = threadIdx.x;
    const int grp  = tid >> 5;      // 0..7
    const int lane = tid & 31;      // 0..31
    const int bid  = blockIdx.x;

    __shared__ __align__(16) float4 part4[8][26];
    __shared__ int   ids[Lx];
    __shared__ float red[Lx];
    __shared__ __align__(16) float ys_sh[104];
    __shared__ __align__(16) float t_sh[104];
    __shared__ float zs_sh[104];
    __shared__ float pt_sh[Kx];
    __shared__ float m_sh[8], s_sh[8], sc_sh[8];

    float* pf = (float*)part4;      // [8][104] float view

    if (bid >= NBLK_ATTN) {
        // ================= NEG-GATHER BLOCK (fp8, 1 line/row) =================
        const int j = bid - NBLK_ATTN;              // 0..2559
        const int b = j / NEG_CHUNKS;
        const int c = j - b * NEG_CHUNKS;
        const int* idp = neg_ids + (size_t)b * NEG_ROWS + c * NEG_CHUNK;

        ids[tid] = idp[tid];
        __syncthreads();

        if (lane < 25) {
            const int o = lane * 4;
            float4 a0 = {0,0,0,0}, a1 = {0,0,0,0}, a2 = {0,0,0,0}, a3 = {0,0,0,0};
            for (int r = grp; r < NEG_CHUNK; r += 32) {
                const unsigned u0 = *(const unsigned*)(tb8 + (size_t)ids[r]      * RS8 + o);
                const unsigned u1 = *(const unsigned*)(tb8 + (size_t)ids[r + 8]  * RS8 + o);
                const unsigned u2 = *(const unsigned*)(tb8 + (size_t)ids[r + 16] * RS8 + o);
                const unsigned u3 = *(const unsigned*)(tb8 + (size_t)ids[r + 24] * RS8 + o);
                const float4 v0 = fp8x4_dec(u0);
                const float4 v1 = fp8x4_dec(u1);
                const float4 v2 = fp8x4_dec(u2);
                const float4 v3 = fp8x4_dec(u3);
                a0.x += v0.x; a0.y += v0.y; a0.z += v0.z; a0.w += v0.w;
                a1.x += v1.x; a1.y += v1.y; a1.z += v1.z; a1.w += v1.w;
                a2.x += v2.x; a2.y += v2.y; a2.z += v2.z; a2.w += v2.w;
                a3.x += v3.x; a3.y += v3.y; a3.z += v3.z; a3.w += v3.w;
            }
            a0.x += a1.x + a2.x + a3.x; a0.y += a1.y + a2.y + a3.y;
            a0.z += a1.z + a2.z + a3.z; a0.w += a1.w + a2.w + a3.w;
            part4[grp][lane] = a0;
        }
        __syncthreads();
        if (tid < Dx) {
            float s = 0.f;
            #pragma unroll
            for (int gg = 0; gg < 8; ++gg) s += pf[gg * 104 + tid];
            atomicAdd(&g[(size_t)b * Dx + tid], s);
        }
        return;
    }

    // ================= ATTN BLOCK =================
    const int b = bid;
    ids[tid] = pos_ids[(size_t)b * Lx + tid];
    __syncthreads();

    // ---- pass A: ys = mean_l e   (fp8, 1 line/row; ys only feeds logits) ----
    if (lane < 25) {
        const int o = lane * 4;
        float4 a0 = {0,0,0,0}, a1 = {0,0,0,0}, a2 = {0,0,0,0}, a3 = {0,0,0,0};
        for (int r = grp; r < Lx; r += 32) {
            const float4 v0 = fp8x4_dec(*(const unsigned*)(tb8 + (size_t)ids[r]      * RS8 + o));
            const float4 v1 = fp8x4_dec(*(const unsigned*)(tb8 + (size_t)ids[r + 8]  * RS8 + o));
            const float4 v2 = fp8x4_dec(*(const unsigned*)(tb8 + (size_t)ids[r + 16] * RS8 + o));
            const float4 v3 = fp8x4_dec(*(const unsigned*)(tb8 + (size_t)ids[r + 24] * RS8 + o));
            a0.x += v0.x; a0.y += v0.y; a0.z += v0.z; a0.w += v0.w;
            a1.x += v1.x; a1.y += v1.y; a1.z += v1.z; a1.w += v1.w;
            a2.x += v2.x; a2.y += v2.y; a2.z += v2.z; a2.w += v2.w;
            a3.x += v3.x; a3.y += v3.y; a3.z += v3.z; a3.w += v3.w;
        }
        a0.x += a1.x + a2.x + a3.x; a0.y += a1.y + a2.y + a3.y;
        a0.z += a1.z + a2.z + a3.z; a0.w += a1.w + a2.w + a3.w;
        part4[grp][lane] = a0;
    }
    __syncthreads();
    if (tid < Dx) {
        float s = 0.f;
        #pragma unroll
        for (int gg = 0; gg < 8; ++gg) s += pf[gg * 104 + tid];
        ys_sh[tid] = s * (1.0f / Lx);
    }
    __syncthreads();

    // ---- t = W_att @ ys ----
    if (tid < Dx) {
        const float* wrow = W_att + (size_t)tid * Dx;
        float s = 0.f;
        #pragma unroll 4
        for (int e = 0; e < Dx; ++e) s += wrow[e] * ys_sh[e];
        t_sh[tid] = s;
    }
    if (tid >= Dx && tid < 104) t_sh[tid] = 0.f;
    __syncthreads();

    // ---- pass B: online softmax, f + zs in one gather (bf16) ----
    {
        const float4 tl = (lane < 25) ? ((const float4*)t_sh)[lane]
                                      : make_float4(0.f, 0.f, 0.f, 0.f);
        float m = -1e30f, ssum = 0.f;
        float4 za = {0.f, 0.f, 0.f, 0.f};
        for (int r = grp; r < Lx; r += 16) {
            const int id0 = ids[r];
            const int id1 = ids[r + 8];
            float4 e0 = {0,0,0,0}, e1 = {0,0,0,0};
            if (lane < 25) {
                e0 = ld_bf4(tb16 + (size_t)id0 * RS16 + lane * 4);
                e1 = ld_bf4(tb16 + (size_t)id1 * RS16 + lane * 4);
            }
            float d0 = dot4(e0, tl);
            float d1 = dot4(e1, tl);
            #pragma unroll
            for (int o = 16; o > 0; o >>= 1) {
                d0 += __shfl_xor(d0, o, 32);
                d1 += __shfl_xor(d1, o, 32);
            }
            const float f0 = (id0 != 0) ? d0 : -1e30f;
            const float f1 = (id1 != 0) ? d1 : -1e30f;
            const float mn = fmaxf(m, fmaxf(f0, f1));
            const float sc = expf(m - mn);
            const float w0 = (id0 != 0) ? expf(d0 - mn) : 0.f;
            const float w1 = (id1 != 0) ? expf(d1 - mn) : 0.f;
            ssum = ssum * sc + w0 + w1;
            za.x = za.x * sc + w0 * e0.x + w1 * e1.x;
            za.y = za.y * sc + w0 * e0.y + w1 * e1.y;
            za.z = za.z * sc + w0 * e0.z + w1 * e1.z;
            za.w = za.w * sc + w0 * e0.w + w1 * e1.w;
            m = mn;
        }
        if (lane == 0) { m_sh[grp] = m; s_sh[grp] = ssum; }
        if (lane < 25) part4[grp][lane] = za;
    }
    __syncthreads();
    if (tid < 8) {
        float M = -1e30f;
        #pragma unroll
        for (int gg = 0; gg < 8; ++gg) M = fmaxf(M, m_sh[gg]);
        sc_sh[tid] = expf(m_sh[tid] - M);
    }
    __syncthreads();
    if (tid < Dx) {
        float S = 0.f, z = 0.f;
        #pragma unroll
        for (int gg = 0; gg < 8; ++gg) {
            S += s_sh[gg] * sc_sh[gg];
            z += pf[gg * 104 + tid] * sc_sh[gg];
        }
        zs_sh[tid] = z / S;
    }
    __syncthreads();

    // ---- pt = sigmoid(zs @ Wk + bk) ----
    if (tid < Kx) {
        float s = bk[tid];
        for (int d = 0; d < Dx; ++d) s += zs_sh[d] * Wk[d * Kx + tid];
        const float pk = 1.0f / (1.0f + expf(-s));
        pt_sh[tid] = pk;
        pt_out[(size_t)b * Kx + tid] = pk;
    }
    __syncthreads();

    // ---- rs = bf + pt @ Wf ; pos partial = rs . zs ----
    float contrib = 0.f;
    if (tid < Dx) {
        float r = bf[tid];
        #pragma unroll
        for (int k = 0; k < Kx; ++k) r += pt_sh[k] * Wf[k * Dx + tid];
        rs_out[(size_t)b * Dx + tid] = r;
        contrib = r * zs_sh[tid];
    }
    red[tid] = contrib;
    __syncthreads();
    for (int s = 128; s > 0; s >>= 1) {
        if (tid < s) red[tid] += red[tid + s];
        __syncthreads();
    }
    if (tid == 0) atomicAdd(&acc[0], red[0]);
}

// ---- loss: neg dot + reg term + final (single block) ----
__global__ __launch_bounds__(1024) void loss_kernel(
    const float* __restrict__ Wf, const float* __restrict__ acc,
    const float* __restrict__ g, const float* __restrict__ rs,
    float* __restrict__ out)
{
    __shared__ float n[Kx];
    __shared__ float red[1024];
    const int tid = threadIdx.x;

    float v = 0.f;
    for (int i = tid; i < Bx * Dx; i += 1024) v += g[i] * rs[i];
    red[tid] = v;
    __syncthreads();
    for (int s = 512; s > 0; s >>= 1) {
        if (tid < s) red[tid] += red[tid + s];
        __syncthreads();
    }
    const float neg_term = red[0] * (1.0f / 64.0f);
    __syncthreads();

    if (tid < Kx) {
        float s = 0.f;
        for (int d = 0; d < Dx; ++d) {
            const float w = Wf[tid * Dx + d];
            s += w * w;
        }
        n[tid] = sqrtf(s);
    }
    __syncthreads();

    float vv = 0.f;
    if (tid < Kx * Kx) {
        const int i = tid / Kx;
        const int j = tid - i * Kx;
        const float x = n[i] * n[j] - 1.0f;
        vv = x * x;
    }
    red[tid] = vv;
    __syncthreads();
    for (int s = 512; s > 0; s >>= 1) {
        if (tid < s) red[tid] += red[tid + s];
        __syncthreads();
    }
    if (tid == 0) {
        const float reg = sqrtf(red[0]);
        const float margin = 1.0f - neg_term + acc[0];
        out[0] = fmaxf(margin, 0.0f) + reg;   // LAMBDA = 1.0
    }
}

extern "C" void kernel_launch(void* const* d_in, const int* in_sizes, int n_in,
                              void* d_out, int out_size, void* d_ws, size_t ws_size,
                              hipStream_t stream) {
    const int*   pos_ids = (const int*)  d_in[0];
    const int*   neg_ids = (const int*)  d_in[1];
    const float* table   = (const float*)d_in[2];
    const float* W_att   = (const float*)d_in[3];
    const float* Wk      = (const float*)d_in[4];
    const float* bk      = (const float*)d_in[5];
    const float* Wf      = (const float*)d_in[6];
    const float* bf      = (const float*)d_in[7];

    float* out    = (float*)d_out;
    float* pt_out = out + 1;
    float* rs_out = out + 1 + (size_t)Bx * Kx;

    // padded layout needs: bf16 12.8 MB + fp8 6.4 MB + acc ~0.2 MB
    const size_t need_pad = (size_t)VROWS * PAD16 * 2 + (size_t)VROWS * PAD8
                          + 16 + (size_t)ACC_N * 4;
    const int padded = (ws_size >= need_pad) ? 1 : 0;
    const int RS16 = padded ? PAD16 : RAW16;
    const int RS8  = padded ? PAD8  : RAW8;

    unsigned short* tb16 = (unsigned short*)d_ws;
    unsigned char*  tb8  = (unsigned char*)d_ws + (size_t)VROWS * RS16 * 2;
    size_t acc_off = (size_t)VROWS * RS16 * 2 + (size_t)VROWS * RS8;
    acc_off = (acc_off + 15) & ~(size_t)15;
    float* acc = (float*)((char*)d_ws + acc_off);
    float* g   = acc + 4;

    const int nthreads = VROWS * 32;
    convert_kernel<<<(nthreads + 255) / 256, 256, 0, stream>>>(
        table, tb16, tb8, acc, RS16, RS8, padded);
    fused_gather<<<NBLK_ATTN + NBLK_NEG, 256, 0, stream>>>(
        pos_ids, neg_ids, tb16, tb8, W_att, Wk, bk, Wf, bf,
        pt_out, rs_out, acc, g, RS16, RS8);
    loss_kernel<<<1, 1024, 0, stream>>>(Wf, acc, g, rs_out, out);
}